// Round 4
// baseline (321.580 us; speedup 1.0000x reference)
//
#include <hip/hip_runtime.h>
#include <hip/hip_bf16.h>
#include <stdint.h>

// ---------------------------------------------------------------------------
// LazyGGUFLinear: y = x @ dequant(scales, codes)^T   (M=N=K=4096)
// R1: 3 kernels, BK=32 GEMM 217us, total 353us.
// R2: BK=64 + XOR swizzle (conflicts 1.68e7 -> 0), GEMM 157.5us = 873 TF
//     (m97 plateau), total 317us.
// R3: cooperative fused kernel -> launch failed outright (no output). Reverted.
// R4: R2 GEMM unchanged; prologue rewritten for full coalescing: one 16B load
//     + one 8B store per thread (R2 prologue used stride-32B lane addressing,
//     2x cache-line touches per load -> ~1.4 TB/s).
// ---------------------------------------------------------------------------

#define M_DIM 4096
#define N_DIM 4096
#define K_DIM 4096
#define TILE 128
#define BK 64

typedef __attribute__((ext_vector_type(8))) short bf16x8;   // 8 bf16 = 4 VGPRs
typedef __attribute__((ext_vector_type(4))) float f32x4;    // MFMA C/D

__device__ __forceinline__ unsigned short f32_to_bf16_rne(float f) {
    unsigned u = __float_as_uint(f);
    u += 0x7fffu + ((u >> 16) & 1u);   // round-to-nearest-even
    return (unsigned short)(u >> 16);
}

__device__ __forceinline__ void load_lds16(const void* g, void* l) {
    // async global->LDS, 16 B per lane; LDS dest = wave-uniform base + lane*16
    __builtin_amdgcn_global_load_lds(
        (const __attribute__((address_space(1))) unsigned int*)g,
        (__attribute__((address_space(3))) unsigned int*)l, 16, 0, 0);
}

// ---- prologue: fully-coalesced, 4 elements/thread --------------------------
// blocks [0,16384): dequant codes -> Wb.  blocks [16384,32768): cvt x -> xb.
// Per thread: one 16B load (lane-contiguous) + one 8B store (lane-contiguous).
__global__ __launch_bounds__(256) void prologue_kernel(
        const int* __restrict__ codes, const float* __restrict__ scales,
        unsigned short* __restrict__ W,
        const float* __restrict__ x, unsigned short* __restrict__ xb) {
    const int bid = blockIdx.x;
    if (bid < 16384) {
        const int tid = bid * 256 + threadIdx.x;      // 0..4,194,303
        // element base = tid*4; o = elem>>12; blk = (elem>>5)&127
        const float s = scales[(tid >> 10) * 128 + ((tid >> 3) & 127)];
        const int4 c = ((const int4*)codes)[tid];     // 16B coalesced
        union { unsigned short u[4]; uint2 v; } p;
        p.u[0] = f32_to_bf16_rne(s * (float)(c.x - 128));
        p.u[1] = f32_to_bf16_rne(s * (float)(c.y - 128));
        p.u[2] = f32_to_bf16_rne(s * (float)(c.z - 128));
        p.u[3] = f32_to_bf16_rne(s * (float)(c.w - 128));
        ((uint2*)W)[tid] = p.v;                       // 8B coalesced
    } else {
        const int tid = (bid - 16384) * 256 + threadIdx.x;
        const float4 f = ((const float4*)x)[tid];     // 16B coalesced
        union { unsigned short u[4]; uint2 v; } p;
        p.u[0] = f32_to_bf16_rne(f.x); p.u[1] = f32_to_bf16_rne(f.y);
        p.u[2] = f32_to_bf16_rne(f.z); p.u[3] = f32_to_bf16_rne(f.w);
        ((uint2*)xb)[tid] = p.v;                      // 8B coalesced
    }
}

// ---- bf16 GEMM, both operands K-major. 128x128 tile, BK=64, 4 waves -------
// (unchanged from R2: 157.5us, 873 TF, SQ_LDS_BANK_CONFLICT = 0)
__global__ __launch_bounds__(256) void gemm_bt_kernel(
        const unsigned short* __restrict__ A,   // [M,K] bf16 (x)
        const unsigned short* __restrict__ B,   // [N,K] bf16 (W)
        float* __restrict__ C) {                // [M,N] fp32
    __shared__ unsigned short As[TILE * BK];    // 16 KB
    __shared__ unsigned short Bs[TILE * BK];    // 16 KB

    const int wave = threadIdx.x >> 6;
    const int lane = threadIdx.x & 63;

    // XCD-rectangle swizzle: xcd = b%8 [m09]; XCD x owns a 16(m) x 8(n)
    // rectangle of the 32x32 tile grid.
    const int b   = blockIdx.x;           // 0..1023
    const int i   = b >> 3;               // 0..127 slot within XCD
    const int mt0 = ((b >> 2) & 1) * 16 + (i & 15);   // 0..31
    const int nt0 = (b & 3) * 8 + (i >> 4);           // 0..31
    const int m0 = mt0 * TILE;
    const int n0 = nt0 * TILE;

    // staging: each inst = 64 lanes x 16B = 8 rows x 64k; 4 insts per operand
    // per wave (wave stages 32 rows). Global k-offset XOR-swizzled by row&7
    // so fragment reads hit all 32 banks.
    const int srow  = lane >> 3;                          // 0..7
    const int skofs = ((lane & 7) ^ srow) * 8;            // XOR swizzle
    const int wrow0 = wave * 32;

    const unsigned short* Ag = A + (size_t)(m0 + wrow0 + srow) * K_DIM + skofs;
    const unsigned short* Bg = B + (size_t)(n0 + wrow0 + srow) * K_DIM + skofs;
    unsigned short* AsBase = &As[wrow0 * BK];   // wave-uniform LDS bases
    unsigned short* BsBase = &Bs[wrow0 * BK];

    // fragment addressing (A-operand layout: row = lane&15, k = quad*8 + j)
    const int frow = lane & 15;
    const int quad = lane >> 4;
    const int wm = (wave >> 1) * 64;        // wave's 64x64 subtile
    const int wn = (wave & 1) * 64;

    f32x4 acc[4][4] = {};

    for (int k0 = 0; k0 < K_DIM; k0 += BK) {
#pragma unroll
        for (int j = 0; j < 4; ++j) {
            load_lds16(Ag + k0 + j * 8 * K_DIM, AsBase + j * 8 * BK);
            load_lds16(Bg + k0 + j * 8 * K_DIM, BsBase + j * 8 * BK);
        }
        __syncthreads();    // drains vmcnt (global_load_lds) + barrier

#pragma unroll
        for (int h = 0; h < 2; ++h) {       // two 16x16x32 K-halves of BK=64
            bf16x8 a[4], bfr[4];
#pragma unroll
            for (int t = 0; t < 4; ++t) {
                const int ar = wm + t * 16 + frow;
                const int br = wn + t * 16 + frow;
                const int ch = (h * 4 + quad) ^ (frow & 7);   // un-XOR
                a[t]   = *(const bf16x8*)&As[ar * BK + ch * 8];
                bfr[t] = *(const bf16x8*)&Bs[br * BK + ch * 8];
            }
#pragma unroll
            for (int mt = 0; mt < 4; ++mt)
#pragma unroll
                for (int nt = 0; nt < 4; ++nt)
                    acc[mt][nt] = __builtin_amdgcn_mfma_f32_16x16x32_bf16(
                        a[mt], bfr[nt], acc[mt][nt], 0, 0, 0);
        }
        __syncthreads();    // protect LDS before next staging overwrite
    }

    // epilogue: C/D layout col = lane&15, row = quad*4 + reg  [m89/m91]
#pragma unroll
    for (int mt = 0; mt < 4; ++mt)
#pragma unroll
        for (int nt = 0; nt < 4; ++nt)
#pragma unroll
            for (int r = 0; r < 4; ++r) {
                const int row = m0 + wm + mt * 16 + quad * 4 + r;
                const int col = n0 + wn + nt * 16 + frow;
                C[(size_t)row * N_DIM + col] = acc[mt][nt][r];
            }
}

extern "C" void kernel_launch(void* const* d_in, const int* in_sizes, int n_in,
                              void* d_out, int out_size, void* d_ws, size_t ws_size,
                              hipStream_t stream) {
    const float* x      = (const float*)d_in[0];   // 2*2048*4096 fp32
    const float* scales = (const float*)d_in[1];   // 4096*128 fp32
    const int*   codes  = (const int*)d_in[2];     // 4096*128*32 int32
    float* y = (float*)d_out;                      // 4096*4096 fp32

    unsigned short* Wb = (unsigned short*)d_ws;                       // 32 MB
    unsigned short* xb = (unsigned short*)((char*)d_ws + (size_t)N_DIM * K_DIM * 2); // 32 MB

    prologue_kernel<<<32768, 256, 0, stream>>>(codes, scales, Wb, x, xb);

    gemm_bt_kernel<<<1024, 256, 0, stream>>>(xb, Wb, y);
}